// Round 17
// baseline (124.960 us; speedup 1.0000x reference)
//
#include <hip/hip_runtime.h>
#include <hip/hip_bf16.h>

typedef _Float16 h8 __attribute__((ext_vector_type(8)));
typedef _Float16 h4 __attribute__((ext_vector_type(4)));
typedef _Float16 h2 __attribute__((ext_vector_type(2)));
typedef float f2 __attribute__((ext_vector_type(2)));
typedef float f4 __attribute__((ext_vector_type(4)));
typedef float f16v __attribute__((ext_vector_type(16)));

#define MFMA32(a, b, c) __builtin_amdgcn_mfma_f32_32x32x16_f16(a, b, c, 0, 0, 0)

static constexpr int DM = 512;
static constexpr int SL = 4096;
static constexpr int NH = 8;
static constexpr int DK = 64;
static constexpr int NB = 2;

__device__ __forceinline__ h2 pk2(float a, float b) {
    return __builtin_bit_cast(h2, __builtin_amdgcn_cvt_pkrtz(a, b));
}
__device__ __forceinline__ h8 cvt8(float4 x, float4 y) {
    union { h2 h[4]; h8 v; } u;
    u.h[0] = pk2(x.x, x.y); u.h[1] = pk2(x.z, x.w);
    u.h[2] = pk2(y.x, y.y); u.h[3] = pk2(y.z, y.w);
    return u.v;
}

// ---------------------------------------------------------------------------
// Kernel 1: fused Q/K/V projections. 128x128 tile, BK=32, MFMA 32x32x16.
// (unchanged, proven)
// ---------------------------------------------------------------------------
__global__ __launch_bounds__(256) void proj_qkv_kernel(
    const float* __restrict__ Qin, const float* __restrict__ Kin,
    const float* __restrict__ Vin,
    const float* __restrict__ Wq, const float* __restrict__ Wk,
    const float* __restrict__ Wv,
    const float* __restrict__ bq, const float* __restrict__ bk,
    const float* __restrict__ bv,
    _Float16* __restrict__ qo, _Float16* __restrict__ ko,
    _Float16* __restrict__ vTo)
{
    const int bid = blockIdx.x;
    const int op  = (bid & 7) * 96 + (bid >> 3);
    const int nt    = op & 3;
    const int panel = op >> 2;
    const int which = panel >> 6;
    const int mt    = panel & 63;

    const float* __restrict__ X    = which == 0 ? Qin : (which == 1 ? Kin : Vin);
    const float* __restrict__ W    = which == 0 ? Wq  : (which == 1 ? Wk  : Wv);
    const float* __restrict__ bias = which == 0 ? bq  : (which == 1 ? bk  : bv);

    __shared__ __align__(16) _Float16 As[2][4096];
    __shared__ __align__(16) _Float16 Bs[2][4096];
    __shared__ __align__(16) _Float16 Vtr[64][144];

    const int t   = threadIdx.x;
    const int w   = t >> 6;
    const int l   = t & 63;
    const int l31 = l & 31;
    const int hi  = l >> 5;
    const int mbase = mt * 128;
    const int nbase = nt * 128;
    const int wm = (w >> 1) * 64;
    const int wn = (w & 1) * 64;

    const int id0 = t, id1 = 256 + t;
    const int r0 = id0 >> 2, c0 = id0 & 3;
    const int r1 = id1 >> 2, c1 = id1 & 3;
    const int sl0 = (c0 ^ (r0 & 3)) * 8;
    const int sl1 = (c1 ^ (r1 & 3)) * 8;
    const float* Xp0 = X + (size_t)(mbase + r0) * DM + c0 * 8;
    const float* Xp1 = X + (size_t)(mbase + r1) * DM + c1 * 8;
    const float* Wp0 = W + (size_t)(nbase + r0) * DM + c0 * 8;
    const float* Wp1 = W + (size_t)(nbase + r1) * DM + c1 * 8;

    f16v acc[2][2] = {};

    {
        float4 a00 = *(const float4*)(Xp0), a01 = *(const float4*)(Xp0 + 4);
        float4 a10 = *(const float4*)(Xp1), a11 = *(const float4*)(Xp1 + 4);
        float4 b00 = *(const float4*)(Wp0), b01 = *(const float4*)(Wp0 + 4);
        float4 b10 = *(const float4*)(Wp1), b11 = *(const float4*)(Wp1 + 4);
        *(h8*)&As[0][r0 * 32 + sl0] = cvt8(a00, a01);
        *(h8*)&As[0][r1 * 32 + sl1] = cvt8(a10, a11);
        *(h8*)&Bs[0][r0 * 32 + sl0] = cvt8(b00, b01);
        *(h8*)&Bs[0][r1 * 32 + sl1] = cvt8(b10, b11);
    }
    __syncthreads();

    int cur = 0;
    for (int step = 0; step < 16; ++step) {
        const int kn = (step + 1) * 32;
        float4 a00, a01, a10, a11, b00, b01, b10, b11;
        const bool more = step + 1 < 16;
        if (more) {
            a00 = *(const float4*)(Xp0 + kn); a01 = *(const float4*)(Xp0 + kn + 4);
            a10 = *(const float4*)(Xp1 + kn); a11 = *(const float4*)(Xp1 + kn + 4);
            b00 = *(const float4*)(Wp0 + kn); b01 = *(const float4*)(Wp0 + kn + 4);
            b10 = *(const float4*)(Wp1 + kn); b11 = *(const float4*)(Wp1 + kn + 4);
        }

        const _Float16* Ac = As[cur];
        const _Float16* Bc = Bs[cur];
        h8 af[2][2], bf[2][2];
#pragma unroll
        for (int ti = 0; ti < 2; ++ti)
#pragma unroll
            for (int s = 0; s < 2; ++s)
                af[ti][s] = *(const h8*)&Ac[(wm + ti * 32 + l31) * 32 +
                                            (((2 * s + hi) ^ (l31 & 3)) << 3)];
#pragma unroll
        for (int tj = 0; tj < 2; ++tj)
#pragma unroll
            for (int s = 0; s < 2; ++s)
                bf[tj][s] = *(const h8*)&Bc[(wn + tj * 32 + l31) * 32 +
                                            (((2 * s + hi) ^ (l31 & 3)) << 3)];
        __builtin_amdgcn_s_setprio(1);
#pragma unroll
        for (int ti = 0; ti < 2; ++ti)
#pragma unroll
            for (int tj = 0; tj < 2; ++tj)
#pragma unroll
                for (int s = 0; s < 2; ++s)
                    acc[ti][tj] = MFMA32(af[ti][s], bf[tj][s], acc[ti][tj]);
        __builtin_amdgcn_s_setprio(0);

        if (more) {
            const int nb2 = cur ^ 1;
            *(h8*)&As[nb2][r0 * 32 + sl0] = cvt8(a00, a01);
            *(h8*)&As[nb2][r1 * 32 + sl1] = cvt8(a10, a11);
            *(h8*)&Bs[nb2][r0 * 32 + sl0] = cvt8(b00, b01);
            *(h8*)&Bs[nb2][r1 * 32 + sl1] = cvt8(b10, b11);
        }
        __syncthreads();
        cur ^= 1;
    }

    if (which < 2) {
        _Float16* dst = (which == 0) ? qo : ko;
#pragma unroll
        for (int tj = 0; tj < 2; ++tj) {
            const int n  = nbase + wn + tj * 32 + l31;
            const float bb = bias[n];
            const int hh = n >> 6;
            const int d  = n & 63;
#pragma unroll
            for (int ti = 0; ti < 2; ++ti) {
#pragma unroll
                for (int j = 0; j < 4; ++j) {
#pragma unroll
                    for (int c = 0; c < 4; ++c) {
                        const int m = mbase + wm + ti * 32 + 8 * j + 4 * hi + c;
                        const int bi = m >> 12;
                        const int s  = m & 4095;
                        dst[((size_t)(bi * NH + hh) * SL + s) * DK + d] =
                            (_Float16)(acc[ti][tj][4 * j + c] + bb);
                    }
                }
            }
        }
    } else {
        const int bi = mbase >> 12;
        const int s0 = mbase & 4095;
#pragma unroll
        for (int nh = 0; nh < 2; ++nh) {
            __syncthreads();
            if ((w & 1) == nh) {
#pragma unroll
                for (int tj = 0; tj < 2; ++tj) {
                    const int d = tj * 32 + l31;
                    const float bb = bias[nbase + nh * 64 + d];
#pragma unroll
                    for (int ti = 0; ti < 2; ++ti) {
#pragma unroll
                        for (int j = 0; j < 4; ++j) {
                            h2 x0 = pk2(acc[ti][tj][4 * j] + bb,
                                        acc[ti][tj][4 * j + 1] + bb);
                            h2 x1 = pk2(acc[ti][tj][4 * j + 2] + bb,
                                        acc[ti][tj][4 * j + 3] + bb);
                            h4 val = {x0[0], x0[1], x1[0], x1[1]};
                            *(h4*)&Vtr[d][wm + ti * 32 + 8 * j + 4 * hi] = val;
                        }
                    }
                }
            }
            __syncthreads();
            {
                const int d = t >> 2, part = t & 3;
                const int hh = nt * 2 + nh;
                _Float16* dstv = vTo + ((size_t)(bi * NH + hh) * DK + d) * SL +
                                 s0 + part * 32;
                h8 v0 = *(const h8*)&Vtr[d][part * 32];
                h8 v1 = *(const h8*)&Vtr[d][part * 32 + 8];
                h8 v2 = *(const h8*)&Vtr[d][part * 32 + 16];
                h8 v3 = *(const h8*)&Vtr[d][part * 32 + 24];
                *(h8*)(dstv)      = v0;
                *(h8*)(dstv + 8)  = v1;
                *(h8*)(dstv + 16) = v2;
                *(h8*)(dstv + 24) = v3;
            }
        }
    }
}

// ---------------------------------------------------------------------------
// Kernel 2: flash attention, high-intensity 4-wave blocks (64 q-rows/wave).
// R17 micro: all s_setprio removed (m190: setprio reinforces/penalizes
// lockstep pairs); bias C-init folded into the st=0 MFMA C-operand
// (removes 64 v_mov per wave-tile).
// ---------------------------------------------------------------------------
static constexpr int QBLK  = 256;
static constexpr int KSPL  = 2;
static constexpr int KHALF = SL / KSPL;   // 2048
static constexpr int NTS   = KHALF / 64;  // 32

__device__ __forceinline__ void stage_tiles(
    _Float16* Ktb, _Float16* Vtb,
    const _Float16* kbh, const _Float16* vbh, int kb, int t)
{
    const int w = t >> 6;
    const char* ksrc = (const char*)(kbh + (size_t)kb * DK);
#pragma unroll
    for (int p = 0; p < 2; ++p) {
        const int c  = p * 256 + t;             // 16B chunk 0..511
        const int kr = c >> 3;
        const int sl = c & 7;
        const int srow = (kr & ~12) | ((kr & 4) << 1) | ((kr & 8) >> 1);
        const int cs = srow * 8 + (sl ^ (kr & 7));
        char* dst = (char*)Ktb + (size_t)(p * 256 + w * 64) * 16;  // wave-uniform
        __builtin_amdgcn_global_load_lds(
            (const __attribute__((address_space(1))) void*)(ksrc + (size_t)cs * 16),
            (__attribute__((address_space(3))) void*)dst, 16, 0, 0);
    }
#pragma unroll
    for (int p = 0; p < 2; ++p) {
        const int c  = p * 256 + t;
        const int d  = c >> 3;
        const int cs = (c & 7) ^ (d & 7);
        const _Float16* src = vbh + (size_t)d * SL + kb + cs * 8;
        char* dst = (char*)Vtb + (size_t)(p * 256 + w * 64) * 16;
        __builtin_amdgcn_global_load_lds(
            (const __attribute__((address_space(1))) void*)src,
            (__attribute__((address_space(3))) void*)dst, 16, 0, 0);
    }
}

__global__ __launch_bounds__(256, 2) void attn_kernel(
    const _Float16* __restrict__ qg, const _Float16* __restrict__ kg,
    const _Float16* __restrict__ vTg, const int* __restrict__ mask,
    _Float16* __restrict__ o_ws, float* __restrict__ l_ws)
{
    const int t   = threadIdx.x;
    const int w   = t >> 6;
    const int l   = t & 63;
    const int l31 = l & 31;
    const int hi  = l >> 5;
    const int r7  = l31 & 7;
    const int hh  = blockIdx.x & 7;
    const int b   = blockIdx.x >> 3;
    const int qt  = blockIdx.y;
    const int split = blockIdx.z;
    const int koff  = split * KHALF;

    const _Float16* qbh = qg  + (size_t)(b * NH + hh) * SL * DK;
    const _Float16* kbh = kg  + (size_t)(b * NH + hh) * SL * DK;
    const _Float16* vbh = vTg + (size_t)(b * NH + hh) * DK * SL;
    const int* mrow = mask + b * SL;

    __shared__ __align__(16) _Float16 Kt[2][4096];
    __shared__ __align__(16) _Float16 Vt[2][4096];
    __shared__ __align__(16) float bias_tab[KHALF];   // 8 KB

    // mask -> f32 bias table for this key half (8 entries/thread, 256 thr)
#pragma unroll
    for (int j = 0; j < 2; ++j) {
        int4 v = *(const int4*)&mrow[koff + t * 8 + j * 4];
        f4 bv;
        bv[0] = v.x ? 0.f : -1e38f; bv[1] = v.y ? 0.f : -1e38f;
        bv[2] = v.z ? 0.f : -1e38f; bv[3] = v.w ? 0.f : -1e38f;
        *(f4*)&bias_tab[t * 8 + j * 4] = bv;
    }

    const _Float16 sch = (_Float16)(0.125f * 1.44269504089f);
    const h8 sc8 = {sch, sch, sch, sch, sch, sch, sch, sch};
    h8 qf[2][4];
#pragma unroll
    for (int qgp = 0; qgp < 2; ++qgp) {
        const _Float16* qp = qbh +
            (size_t)(qt * QBLK + w * 64 + qgp * 32 + l31) * DK + hi * 8;
#pragma unroll
        for (int st = 0; st < 4; ++st)
            qf[qgp][st] = *(const h8*)(qp + st * 16) * sc8;
    }

    stage_tiles(Kt[0], Vt[0], kbh, vbh, koff, t);
    __syncthreads();

    f16v ov[2][2] = {};        // [d-group][q-group]
    float lsum0 = 0.f, lsum1 = 0.f;
    const h2 one2 = {(_Float16)1.0f, (_Float16)1.0f};

    int cur = 0;
    for (int kt = 0; kt < NTS; ++kt) {
        const int kb = koff + kt * 64;
        if (kt + 1 < NTS)
            stage_tiles(Kt[cur ^ 1], Vt[cur ^ 1], kbh, vbh, kb + 64, t);

        const _Float16* Kc = Kt[cur];
        const _Float16* Vc = Vt[cur];
        const int lb = kt * 64;   // local bias base

        // QK: bias loaded as C-operand of the st=0 MFMA (no copies);
        // one K-fragment load feeds both q-group MFMAs.
        f16v sc[2][2];
#pragma unroll
        for (int kgp = 0; kgp < 2; ++kgp) {
            union { f2 q[8]; f16v v; } u;
#pragma unroll
            for (int j = 0; j < 4; ++j) {
                const int base = lb + kgp * 32 + ((j >> 1) << 4) +
                                 ((j & 1) << 2) + (hi << 3);
                u.q[2 * j]     = *(const f2*)&bias_tab[base];
                u.q[2 * j + 1] = *(const f2*)&bias_tab[base + 2];
            }
            const int rb = (kgp * 32 + l31) * 64;
            h8 a0 = *(const h8*)&Kc[rb + ((hi ^ r7) << 3)];
            sc[kgp][0] = MFMA32(a0, qf[0][0], u.v);
            sc[kgp][1] = MFMA32(a0, qf[1][0], u.v);
#pragma unroll
            for (int st = 1; st < 4; ++st) {
                h8 a = *(const h8*)&Kc[rb + (((st * 2 + hi) ^ r7) << 3)];
                sc[kgp][0] = MFMA32(a, qf[0][st], sc[kgp][0]);
                sc[kgp][1] = MFMA32(a, qf[1][st], sc[kgp][1]);
            }
        }

#pragma unroll
        for (int kgp = 0; kgp < 2; ++kgp)
#pragma unroll
            for (int qgp = 0; qgp < 2; ++qgp)
#pragma unroll
                for (int r = 0; r < 16; ++r)
                    sc[kgp][qgp][r] = __builtin_amdgcn_exp2f(sc[kgp][qgp][r]);

        // PV: one V-fragment load feeds both q-group MFMAs
#pragma unroll
        for (int ks = 0; ks < 4; ++ks) {
            const int kgp = ks >> 1;
            const int e0  = (ks & 1) * 8;
            union { h2 h[4]; h8 v; } pf0, pf1;
#pragma unroll
            for (int u2 = 0; u2 < 4; ++u2) {
                pf0.h[u2] = pk2(sc[kgp][0][e0 + 2 * u2], sc[kgp][0][e0 + 2 * u2 + 1]);
                lsum0 = __builtin_amdgcn_fdot2(pf0.h[u2], one2, lsum0, false);
                pf1.h[u2] = pk2(sc[kgp][1][e0 + 2 * u2], sc[kgp][1][e0 + 2 * u2 + 1]);
                lsum1 = __builtin_amdgcn_fdot2(pf1.h[u2], one2, lsum1, false);
            }
#pragma unroll
            for (int ds = 0; ds < 2; ++ds) {
                h8 av = *(const h8*)&Vc[(ds * 32 + l31) * 64 +
                                        (((ks * 2 + hi) ^ r7) << 3)];
                ov[ds][0] = MFMA32(av, pf0.v, ov[ds][0]);
                ov[ds][1] = MFMA32(av, pf1.v, ov[ds][1]);
            }
        }

        __syncthreads();
        cur ^= 1;
    }

    // epilogue per q-group
    const float osc = 0x1p-12f;
#pragma unroll
    for (int qgp = 0; qgp < 2; ++qgp) {
        float ls = qgp ? lsum1 : lsum0;
        ls += __shfl_xor(ls, 32);
        const int qrow = qt * QBLK + w * 64 + qgp * 32 + l31;
        if (hi == 0)
            l_ws[((size_t)(split * NB + b) * SL + qrow) * NH + hh] = ls * 0x1p-12f;

        _Float16* orow = o_ws +
            ((size_t)split * NB * SL + (size_t)b * SL + qrow) * DM + hh * DK;
#pragma unroll
        for (int ds = 0; ds < 2; ++ds) {
#pragma unroll
            for (int j = 0; j < 4; ++j) {
                const int d0 = ds * 32 + j * 8 + hi * 4;
                h2 w0 = pk2(ov[ds][qgp][4 * j] * osc,     ov[ds][qgp][4 * j + 1] * osc);
                h2 w1 = pk2(ov[ds][qgp][4 * j + 2] * osc, ov[ds][qgp][4 * j + 3] * osc);
                h4 val = {w0[0], w0[1], w1[0], w1[1]};
                *(h4*)&orow[d0] = val;
            }
        }
    }
}

// ---------------------------------------------------------------------------
// Kernel 3: output projection, 64x128 tile (grid 512 = 2 blocks/CU), fused
// 2-way split-combine: A = (o0+o1) * (1/(l0+l1)). (unchanged, proven)
// ---------------------------------------------------------------------------
__global__ __launch_bounds__(256) void out_proj_kernel(
    const _Float16* __restrict__ o_ws, const float* __restrict__ l_ws,
    const float* __restrict__ Wo, const float* __restrict__ bo,
    float* __restrict__ out)
{
    const int bid = blockIdx.x;
    const int op  = (bid & 7) * 64 + (bid >> 3);   // 512 = 8 * 64
    const int nt  = op & 3;
    const int mt  = op >> 2;                       // 0..127

    __shared__ __align__(16) _Float16 As[2][2048];   // [64][32]
    __shared__ __align__(16) _Float16 Bs[2][4096];   // [128][32]
    __shared__ float Linv[64][8];

    const int t   = threadIdx.x;
    const int w   = t >> 6;
    const int l   = t & 63;
    const int l31 = l & 31;
    const int hi  = l >> 5;
    const int mbase = mt * 64;
    const int nbase = nt * 128;

    const size_t NSL = (size_t)NB * SL;

#pragma unroll
    for (int e = 0; e < 2; ++e) {
        const int idx = t * 2 + e;
        const int r = idx >> 3, h = idx & 7;
        const int m = mbase + r;
        const int bb = m >> 12;
        const int qr = m & 4095;
        float s = 0.f;
#pragma unroll
        for (int sp = 0; sp < KSPL; ++sp)
            s += l_ws[((size_t)(sp * NB + bb) * SL + qr) * NH + h];
        Linv[r][h] = 1.0f / s;
    }

    const int ar = t >> 2, ac = t & 3;
    const int asl = (ac ^ (ar & 3)) * 8;
    const _Float16* Ap = o_ws + (size_t)(mbase + ar) * DM + ac * 8;

    const int id0 = t, id1 = 256 + t;
    const int r0 = id0 >> 2, c0 = id0 & 3;
    const int r1 = id1 >> 2, c1 = id1 & 3;
    const int sl0 = (c0 ^ (r0 & 3)) * 8;
    const int sl1 = (c1 ^ (r1 & 3)) * 8;
    const float* Wp0 = Wo + (size_t)(nbase + r0) * DM + c0 * 8;
    const float* Wp1 = Wo + (size_t)(nbase + r1) * DM + c1 * 8;

    __syncthreads();  // Linv ready

    auto combine = [&](int kk) -> h8 {
        h8 x0 = *(const h8*)(Ap + kk);
        h8 x1 = *(const h8*)(Ap + kk + NSL * DM);
        const float li = Linv[ar][((kk + ac * 8) >> 6) & 7];
        union { h2 h[4]; h8 v; } u;
#pragma unroll
        for (int e = 0; e < 4; ++e) {
            float a0 = ((float)x0[2 * e]     + (float)x1[2 * e])     * li;
            float a1 = ((float)x0[2 * e + 1] + (float)x1[2 * e + 1]) * li;
            u.h[e] = pk2(a0, a1);
        }
        return u.v;
    };

    f16v acc[2] = {};

    {
        *(h8*)&As[0][ar * 32 + asl] = combine(0);
        float4 b00 = *(const float4*)(Wp0), b01 = *(const float4*)(Wp0 + 4);
        float4 b10 = *(const float4*)(Wp1), b11 = *(const float4*)(Wp1 + 4);
        *(h8*)&Bs[0][r0 * 32 + sl0] = cvt8(b00, b01);
        *(h8*)&Bs[0][r1 * 32 + sl1] = cvt8(b10, b11);
    }
    __syncthreads();

    int cur = 0;
    for (int step = 0; step < 16; ++step) {
        const int kn = (step + 1) * 32;
        const bool more = step + 1 < 16;
        h8 av;
        float4 b00, b01, b10, b11;
        if (more) {
            av  = combine(kn);
            b00 = *(const float4*)(Wp0 + kn); b01 = *(const float4*)(Wp0 + kn + 4);
            b10 = *(const float4*)(Wp1 + kn); b11 = *(const float4*)(Wp1 + kn + 4);
        }

        const _Float16* Ac = As[cur];
        const _Float16* Bc = Bs[cur];
        h8 af[2][2], bf[2];
#pragma unroll
        for (int ti = 0; ti < 2; ++ti)
#pragma unroll
            for (int s = 0; s < 2; ++s)
                af[ti][s] = *(const h8*)&Ac[(ti * 32 + l31) * 32 +
                                            (((2 * s + hi) ^ (l31 & 3)) << 3)];
#pragma unroll
        for (int s = 0; s < 2; ++s)
            bf[s] = *(const h8*)&Bc[(w * 32 + l31) * 32 +
                                    (((2 * s + hi) ^ (l31 & 3)) << 3)];
        __builtin_amdgcn_s_setprio(1);
#pragma unroll
        for (int ti = 0; ti < 2; ++ti)
#pragma unroll
            for (int s = 0; s < 2; ++s)
                acc[ti] = MFMA32(af[ti][s], bf[s], acc[ti]);
        __builtin_amdgcn_s_setprio(0);

        if (more) {
            const int nb2 = cur ^ 1;
            *(h8*)&As[nb2][ar * 32 + asl] = av;
            *(h8*)&Bs[nb2][r0 * 32 + sl0] = cvt8(b00, b01);
            *(h8*)&Bs[nb2][r1 * 32 + sl1] = cvt8(b10, b11);
        }
        __syncthreads();
        cur ^= 1;
    }

    const int n = nbase + w * 32 + l31;
    const float bb = bo[n];
#pragma unroll
    for (int ti = 0; ti < 2; ++ti) {
#pragma unroll
        for (int j = 0; j < 4; ++j) {
#pragma unroll
            for (int c = 0; c < 4; ++c) {
                const int m = mbase + ti * 32 + 8 * j + 4 * hi + c;
                out[(size_t)m * DM + n] = acc[ti][4 * j + c] + bb;
            }
        }
    }
}

// ---------------------------------------------------------------------------
extern "C" void kernel_launch(void* const* d_in, const int* in_sizes, int n_in,
                              void* d_out, int out_size, void* d_ws, size_t ws_size,
                              hipStream_t stream)
{
    const float* Q    = (const float*)d_in[0];
    const float* K    = (const float*)d_in[1];
    const float* V    = (const float*)d_in[2];
    const int*   mask = (const int*)d_in[3];
    const float* Wq   = (const float*)d_in[4];
    const float* bq   = (const float*)d_in[5];
    const float* Wk   = (const float*)d_in[6];
    const float* bk   = (const float*)d_in[7];
    const float* Wv   = (const float*)d_in[8];
    const float* bv   = (const float*)d_in[9];
    const float* Wo   = (const float*)d_in[10];
    const float* bo   = (const float*)d_in[11];
    float* out = (float*)d_out;

    _Float16* ws = (_Float16*)d_ws;
    const size_t per = (size_t)NB * NH * SL * DK;  // 4,194,304 halves
    _Float16* q_ws  = ws;
    _Float16* k_ws  = ws + per;
    _Float16* vT_ws = ws + 2 * per;
    _Float16* o_ws  = ws + 3 * per;                       // KSPL * per halves
    float*    l_ws  = (float*)(ws + 3 * per + KSPL * per);

    proj_qkv_kernel<<<dim3(768), 256, 0, stream>>>(
        Q, K, V, Wq, Wk, Wv, bq, bk, bv, q_ws, k_ws, vT_ws);

    attn_kernel<<<dim3(NB * NH, SL / QBLK, KSPL), 256, 0, stream>>>(
        q_ws, k_ws, vT_ws, mask, o_ws, l_ws);

    out_proj_kernel<<<dim3(512), 256, 0, stream>>>(o_ws, l_ws, Wo, bo, out);
}

// Round 18
// 121.971 us; speedup vs baseline: 1.0245x; 1.0245x over previous
//
#include <hip/hip_runtime.h>
#include <hip/hip_bf16.h>

typedef _Float16 h8 __attribute__((ext_vector_type(8)));
typedef _Float16 h4 __attribute__((ext_vector_type(4)));
typedef _Float16 h2 __attribute__((ext_vector_type(2)));
typedef float f2 __attribute__((ext_vector_type(2)));
typedef float f4 __attribute__((ext_vector_type(4)));
typedef float f16v __attribute__((ext_vector_type(16)));

#define MFMA32(a, b, c) __builtin_amdgcn_mfma_f32_32x32x16_f16(a, b, c, 0, 0, 0)

static constexpr int DM = 512;
static constexpr int SL = 4096;
static constexpr int NH = 8;
static constexpr int DK = 64;
static constexpr int NB = 2;

__device__ __forceinline__ h2 pk2(float a, float b) {
    return __builtin_bit_cast(h2, __builtin_amdgcn_cvt_pkrtz(a, b));
}
__device__ __forceinline__ h8 cvt8(float4 x, float4 y) {
    union { h2 h[4]; h8 v; } u;
    u.h[0] = pk2(x.x, x.y); u.h[1] = pk2(x.z, x.w);
    u.h[2] = pk2(y.x, y.y); u.h[3] = pk2(y.z, y.w);
    return u.v;
}

// ---------------------------------------------------------------------------
// Kernel 1: fused Q/K/V projections. 128x128 tile, BK=32, MFMA 32x32x16.
// ---------------------------------------------------------------------------
__global__ __launch_bounds__(256) void proj_qkv_kernel(
    const float* __restrict__ Qin, const float* __restrict__ Kin,
    const float* __restrict__ Vin,
    const float* __restrict__ Wq, const float* __restrict__ Wk,
    const float* __restrict__ Wv,
    const float* __restrict__ bq, const float* __restrict__ bk,
    const float* __restrict__ bv,
    _Float16* __restrict__ qo, _Float16* __restrict__ ko,
    _Float16* __restrict__ vTo)
{
    const int bid = blockIdx.x;
    const int op  = (bid & 7) * 96 + (bid >> 3);
    const int nt    = op & 3;
    const int panel = op >> 2;
    const int which = panel >> 6;
    const int mt    = panel & 63;

    const float* __restrict__ X    = which == 0 ? Qin : (which == 1 ? Kin : Vin);
    const float* __restrict__ W    = which == 0 ? Wq  : (which == 1 ? Wk  : Wv);
    const float* __restrict__ bias = which == 0 ? bq  : (which == 1 ? bk  : bv);

    __shared__ __align__(16) _Float16 As[2][4096];
    __shared__ __align__(16) _Float16 Bs[2][4096];
    __shared__ __align__(16) _Float16 Vtr[64][144];

    const int t   = threadIdx.x;
    const int w   = t >> 6;
    const int l   = t & 63;
    const int l31 = l & 31;
    const int hi  = l >> 5;
    const int mbase = mt * 128;
    const int nbase = nt * 128;
    const int wm = (w >> 1) * 64;
    const int wn = (w & 1) * 64;

    const int id0 = t, id1 = 256 + t;
    const int r0 = id0 >> 2, c0 = id0 & 3;
    const int r1 = id1 >> 2, c1 = id1 & 3;
    const int sl0 = (c0 ^ (r0 & 3)) * 8;
    const int sl1 = (c1 ^ (r1 & 3)) * 8;
    const float* Xp0 = X + (size_t)(mbase + r0) * DM + c0 * 8;
    const float* Xp1 = X + (size_t)(mbase + r1) * DM + c1 * 8;
    const float* Wp0 = W + (size_t)(nbase + r0) * DM + c0 * 8;
    const float* Wp1 = W + (size_t)(nbase + r1) * DM + c1 * 8;

    f16v acc[2][2] = {};

    {
        float4 a00 = *(const float4*)(Xp0), a01 = *(const float4*)(Xp0 + 4);
        float4 a10 = *(const float4*)(Xp1), a11 = *(const float4*)(Xp1 + 4);
        float4 b00 = *(const float4*)(Wp0), b01 = *(const float4*)(Wp0 + 4);
        float4 b10 = *(const float4*)(Wp1), b11 = *(const float4*)(Wp1 + 4);
        *(h8*)&As[0][r0 * 32 + sl0] = cvt8(a00, a01);
        *(h8*)&As[0][r1 * 32 + sl1] = cvt8(a10, a11);
        *(h8*)&Bs[0][r0 * 32 + sl0] = cvt8(b00, b01);
        *(h8*)&Bs[0][r1 * 32 + sl1] = cvt8(b10, b11);
    }
    __syncthreads();

    int cur = 0;
    for (int step = 0; step < 16; ++step) {
        const int kn = (step + 1) * 32;
        float4 a00, a01, a10, a11, b00, b01, b10, b11;
        const bool more = step + 1 < 16;
        if (more) {
            a00 = *(const float4*)(Xp0 + kn); a01 = *(const float4*)(Xp0 + kn + 4);
            a10 = *(const float4*)(Xp1 + kn); a11 = *(const float4*)(Xp1 + kn + 4);
            b00 = *(const float4*)(Wp0 + kn); b01 = *(const float4*)(Wp0 + kn + 4);
            b10 = *(const float4*)(Wp1 + kn); b11 = *(const float4*)(Wp1 + kn + 4);
        }

        const _Float16* Ac = As[cur];
        const _Float16* Bc = Bs[cur];
        h8 af[2][2], bf[2][2];
#pragma unroll
        for (int ti = 0; ti < 2; ++ti)
#pragma unroll
            for (int s = 0; s < 2; ++s)
                af[ti][s] = *(const h8*)&Ac[(wm + ti * 32 + l31) * 32 +
                                            (((2 * s + hi) ^ (l31 & 3)) << 3)];
#pragma unroll
        for (int tj = 0; tj < 2; ++tj)
#pragma unroll
            for (int s = 0; s < 2; ++s)
                bf[tj][s] = *(const h8*)&Bc[(wn + tj * 32 + l31) * 32 +
                                            (((2 * s + hi) ^ (l31 & 3)) << 3)];
        __builtin_amdgcn_s_setprio(1);
#pragma unroll
        for (int ti = 0; ti < 2; ++ti)
#pragma unroll
            for (int tj = 0; tj < 2; ++tj)
#pragma unroll
                for (int s = 0; s < 2; ++s)
                    acc[ti][tj] = MFMA32(af[ti][s], bf[tj][s], acc[ti][tj]);
        __builtin_amdgcn_s_setprio(0);

        if (more) {
            const int nb2 = cur ^ 1;
            *(h8*)&As[nb2][r0 * 32 + sl0] = cvt8(a00, a01);
            *(h8*)&As[nb2][r1 * 32 + sl1] = cvt8(a10, a11);
            *(h8*)&Bs[nb2][r0 * 32 + sl0] = cvt8(b00, b01);
            *(h8*)&Bs[nb2][r1 * 32 + sl1] = cvt8(b10, b11);
        }
        __syncthreads();
        cur ^= 1;
    }

    if (which < 2) {
        _Float16* dst = (which == 0) ? qo : ko;
#pragma unroll
        for (int tj = 0; tj < 2; ++tj) {
            const int n  = nbase + wn + tj * 32 + l31;
            const float bb = bias[n];
            const int hh = n >> 6;
            const int d  = n & 63;
#pragma unroll
            for (int ti = 0; ti < 2; ++ti) {
#pragma unroll
                for (int j = 0; j < 4; ++j) {
#pragma unroll
                    for (int c = 0; c < 4; ++c) {
                        const int m = mbase + wm + ti * 32 + 8 * j + 4 * hi + c;
                        const int bi = m >> 12;
                        const int s  = m & 4095;
                        dst[((size_t)(bi * NH + hh) * SL + s) * DK + d] =
                            (_Float16)(acc[ti][tj][4 * j + c] + bb);
                    }
                }
            }
        }
    } else {
        const int bi = mbase >> 12;
        const int s0 = mbase & 4095;
#pragma unroll
        for (int nh = 0; nh < 2; ++nh) {
            __syncthreads();
            if ((w & 1) == nh) {
#pragma unroll
                for (int tj = 0; tj < 2; ++tj) {
                    const int d = tj * 32 + l31;
                    const float bb = bias[nbase + nh * 64 + d];
#pragma unroll
                    for (int ti = 0; ti < 2; ++ti) {
#pragma unroll
                        for (int j = 0; j < 4; ++j) {
                            h2 x0 = pk2(acc[ti][tj][4 * j] + bb,
                                        acc[ti][tj][4 * j + 1] + bb);
                            h2 x1 = pk2(acc[ti][tj][4 * j + 2] + bb,
                                        acc[ti][tj][4 * j + 3] + bb);
                            h4 val = {x0[0], x0[1], x1[0], x1[1]};
                            *(h4*)&Vtr[d][wm + ti * 32 + 8 * j + 4 * hi] = val;
                        }
                    }
                }
            }
            __syncthreads();
            {
                const int d = t >> 2, part = t & 3;
                const int hh = nt * 2 + nh;
                _Float16* dstv = vTo + ((size_t)(bi * NH + hh) * DK + d) * SL +
                                 s0 + part * 32;
                h8 v0 = *(const h8*)&Vtr[d][part * 32];
                h8 v1 = *(const h8*)&Vtr[d][part * 32 + 8];
                h8 v2 = *(const h8*)&Vtr[d][part * 32 + 16];
                h8 v3 = *(const h8*)&Vtr[d][part * 32 + 24];
                *(h8*)(dstv)      = v0;
                *(h8*)(dstv + 8)  = v1;
                *(h8*)(dstv + 16) = v2;
                *(h8*)(dstv + 24) = v3;
            }
        }
    }
}

// ---------------------------------------------------------------------------
// Kernel 2: flash attention, high-intensity 4-wave blocks (64 q-rows/wave),
// QBLK=256, KSPL=2, KVB=64. R16-proven best: setprio around MFMA clusters,
// bias C-init via register copies, fdot2 lsum. 104 VGPR + 128 acc-AGPR ->
// 2 waves/SIMD; K/V b128 fragments each feed two q-group MFMAs.
// ---------------------------------------------------------------------------
static constexpr int QBLK  = 256;
static constexpr int KSPL  = 2;
static constexpr int KHALF = SL / KSPL;   // 2048
static constexpr int NTS   = KHALF / 64;  // 32

__device__ __forceinline__ void stage_tiles(
    _Float16* Ktb, _Float16* Vtb,
    const _Float16* kbh, const _Float16* vbh, int kb, int t)
{
    const int w = t >> 6;
    const char* ksrc = (const char*)(kbh + (size_t)kb * DK);
#pragma unroll
    for (int p = 0; p < 2; ++p) {
        const int c  = p * 256 + t;             // 16B chunk 0..511
        const int kr = c >> 3;
        const int sl = c & 7;
        const int srow = (kr & ~12) | ((kr & 4) << 1) | ((kr & 8) >> 1);
        const int cs = srow * 8 + (sl ^ (kr & 7));
        char* dst = (char*)Ktb + (size_t)(p * 256 + w * 64) * 16;  // wave-uniform
        __builtin_amdgcn_global_load_lds(
            (const __attribute__((address_space(1))) void*)(ksrc + (size_t)cs * 16),
            (__attribute__((address_space(3))) void*)dst, 16, 0, 0);
    }
#pragma unroll
    for (int p = 0; p < 2; ++p) {
        const int c  = p * 256 + t;
        const int d  = c >> 3;
        const int cs = (c & 7) ^ (d & 7);
        const _Float16* src = vbh + (size_t)d * SL + kb + cs * 8;
        char* dst = (char*)Vtb + (size_t)(p * 256 + w * 64) * 16;
        __builtin_amdgcn_global_load_lds(
            (const __attribute__((address_space(1))) void*)src,
            (__attribute__((address_space(3))) void*)dst, 16, 0, 0);
    }
}

__global__ __launch_bounds__(256, 2) void attn_kernel(
    const _Float16* __restrict__ qg, const _Float16* __restrict__ kg,
    const _Float16* __restrict__ vTg, const int* __restrict__ mask,
    _Float16* __restrict__ o_ws, float* __restrict__ l_ws)
{
    const int t   = threadIdx.x;
    const int w   = t >> 6;
    const int l   = t & 63;
    const int l31 = l & 31;
    const int hi  = l >> 5;
    const int r7  = l31 & 7;
    const int hh  = blockIdx.x & 7;
    const int b   = blockIdx.x >> 3;
    const int qt  = blockIdx.y;
    const int split = blockIdx.z;
    const int koff  = split * KHALF;

    const _Float16* qbh = qg  + (size_t)(b * NH + hh) * SL * DK;
    const _Float16* kbh = kg  + (size_t)(b * NH + hh) * SL * DK;
    const _Float16* vbh = vTg + (size_t)(b * NH + hh) * DK * SL;
    const int* mrow = mask + b * SL;

    __shared__ __align__(16) _Float16 Kt[2][4096];
    __shared__ __align__(16) _Float16 Vt[2][4096];
    __shared__ __align__(16) float bias_tab[KHALF];   // 8 KB

    // mask -> f32 bias table for this key half (8 entries/thread, 256 thr)
#pragma unroll
    for (int j = 0; j < 2; ++j) {
        int4 v = *(const int4*)&mrow[koff + t * 8 + j * 4];
        f4 bv;
        bv[0] = v.x ? 0.f : -1e38f; bv[1] = v.y ? 0.f : -1e38f;
        bv[2] = v.z ? 0.f : -1e38f; bv[3] = v.w ? 0.f : -1e38f;
        *(f4*)&bias_tab[t * 8 + j * 4] = bv;
    }

    const _Float16 sch = (_Float16)(0.125f * 1.44269504089f);
    const h8 sc8 = {sch, sch, sch, sch, sch, sch, sch, sch};
    h8 qf[2][4];
#pragma unroll
    for (int qgp = 0; qgp < 2; ++qgp) {
        const _Float16* qp = qbh +
            (size_t)(qt * QBLK + w * 64 + qgp * 32 + l31) * DK + hi * 8;
#pragma unroll
        for (int st = 0; st < 4; ++st)
            qf[qgp][st] = *(const h8*)(qp + st * 16) * sc8;
    }

    stage_tiles(Kt[0], Vt[0], kbh, vbh, koff, t);
    __syncthreads();

    f16v ov[2][2] = {};        // [d-group][q-group]
    float lsum0 = 0.f, lsum1 = 0.f;
    const h2 one2 = {(_Float16)1.0f, (_Float16)1.0f};

    int cur = 0;
    for (int kt = 0; kt < NTS; ++kt) {
        const int kb = koff + kt * 64;
        if (kt + 1 < NTS)
            stage_tiles(Kt[cur ^ 1], Vt[cur ^ 1], kbh, vbh, kb + 64, t);

        const _Float16* Kc = Kt[cur];
        const _Float16* Vc = Vt[cur];
        const int lb = kt * 64;   // local bias base

        // C-init bias (per-key, same for both q-groups)
        f16v sc[2][2];
#pragma unroll
        for (int kgp = 0; kgp < 2; ++kgp) {
            union { f2 q[8]; f16v v; } u;
#pragma unroll
            for (int j = 0; j < 4; ++j) {
                const int base = lb + kgp * 32 + ((j >> 1) << 4) +
                                 ((j & 1) << 2) + (hi << 3);
                u.q[2 * j]     = *(const f2*)&bias_tab[base];
                u.q[2 * j + 1] = *(const f2*)&bias_tab[base + 2];
            }
            sc[kgp][0] = u.v;
            sc[kgp][1] = u.v;
        }

        // QK: one K-fragment load feeds both q-group MFMAs
        __builtin_amdgcn_s_setprio(1);
#pragma unroll
        for (int kgp = 0; kgp < 2; ++kgp) {
            const int rb = (kgp * 32 + l31) * 64;
#pragma unroll
            for (int st = 0; st < 4; ++st) {
                h8 a = *(const h8*)&Kc[rb + (((st * 2 + hi) ^ r7) << 3)];
                sc[kgp][0] = MFMA32(a, qf[0][st], sc[kgp][0]);
                sc[kgp][1] = MFMA32(a, qf[1][st], sc[kgp][1]);
            }
        }
        __builtin_amdgcn_s_setprio(0);

#pragma unroll
        for (int kgp = 0; kgp < 2; ++kgp)
#pragma unroll
            for (int qgp = 0; qgp < 2; ++qgp)
#pragma unroll
                for (int r = 0; r < 16; ++r)
                    sc[kgp][qgp][r] = __builtin_amdgcn_exp2f(sc[kgp][qgp][r]);

        // PV: one V-fragment load feeds both q-group MFMAs
        __builtin_amdgcn_s_setprio(1);
#pragma unroll
        for (int ks = 0; ks < 4; ++ks) {
            const int kgp = ks >> 1;
            const int e0  = (ks & 1) * 8;
            union { h2 h[4]; h8 v; } pf0, pf1;
#pragma unroll
            for (int u2 = 0; u2 < 4; ++u2) {
                pf0.h[u2] = pk2(sc[kgp][0][e0 + 2 * u2], sc[kgp][0][e0 + 2 * u2 + 1]);
                lsum0 = __builtin_amdgcn_fdot2(pf0.h[u2], one2, lsum0, false);
                pf1.h[u2] = pk2(sc[kgp][1][e0 + 2 * u2], sc[kgp][1][e0 + 2 * u2 + 1]);
                lsum1 = __builtin_amdgcn_fdot2(pf1.h[u2], one2, lsum1, false);
            }
#pragma unroll
            for (int ds = 0; ds < 2; ++ds) {
                h8 av = *(const h8*)&Vc[(ds * 32 + l31) * 64 +
                                        (((ks * 2 + hi) ^ r7) << 3)];
                ov[ds][0] = MFMA32(av, pf0.v, ov[ds][0]);
                ov[ds][1] = MFMA32(av, pf1.v, ov[ds][1]);
            }
        }
        __builtin_amdgcn_s_setprio(0);

        __syncthreads();
        cur ^= 1;
    }

    // epilogue per q-group
    const float osc = 0x1p-12f;
#pragma unroll
    for (int qgp = 0; qgp < 2; ++qgp) {
        float ls = qgp ? lsum1 : lsum0;
        ls += __shfl_xor(ls, 32);
        const int qrow = qt * QBLK + w * 64 + qgp * 32 + l31;
        if (hi == 0)
            l_ws[((size_t)(split * NB + b) * SL + qrow) * NH + hh] = ls * 0x1p-12f;

        _Float16* orow = o_ws +
            ((size_t)split * NB * SL + (size_t)b * SL + qrow) * DM + hh * DK;
#pragma unroll
        for (int ds = 0; ds < 2; ++ds) {
#pragma unroll
            for (int j = 0; j < 4; ++j) {
                const int d0 = ds * 32 + j * 8 + hi * 4;
                h2 w0 = pk2(ov[ds][qgp][4 * j] * osc,     ov[ds][qgp][4 * j + 1] * osc);
                h2 w1 = pk2(ov[ds][qgp][4 * j + 2] * osc, ov[ds][qgp][4 * j + 3] * osc);
                h4 val = {w0[0], w0[1], w1[0], w1[1]};
                *(h4*)&orow[d0] = val;
            }
        }
    }
}

// ---------------------------------------------------------------------------
// Kernel 3: output projection, 64x128 tile (grid 512 = 2 blocks/CU), fused
// 2-way split-combine: A = (o0+o1) * (1/(l0+l1)).
// ---------------------------------------------------------------------------
__global__ __launch_bounds__(256) void out_proj_kernel(
    const _Float16* __restrict__ o_ws, const float* __restrict__ l_ws,
    const float* __restrict__ Wo, const float* __restrict__ bo,
    float* __restrict__ out)
{
    const int bid = blockIdx.x;
    const int op  = (bid & 7) * 64 + (bid >> 3);   // 512 = 8 * 64
    const int nt  = op & 3;
    const int mt  = op >> 2;                       // 0..127

    __shared__ __align__(16) _Float16 As[2][2048];   // [64][32]
    __shared__ __align__(16) _Float16 Bs[2][4096];   // [128][32]
    __shared__ float Linv[64][8];

    const int t   = threadIdx.x;
    const int w   = t >> 6;
    const int l   = t & 63;
    const int l31 = l & 31;
    const int hi  = l >> 5;
    const int mbase = mt * 64;
    const int nbase = nt * 128;

    const size_t NSL = (size_t)NB * SL;

#pragma unroll
    for (int e = 0; e < 2; ++e) {
        const int idx = t * 2 + e;
        const int r = idx >> 3, h = idx & 7;
        const int m = mbase + r;
        const int bb = m >> 12;
        const int qr = m & 4095;
        float s = 0.f;
#pragma unroll
        for (int sp = 0; sp < KSPL; ++sp)
            s += l_ws[((size_t)(sp * NB + bb) * SL + qr) * NH + h];
        Linv[r][h] = 1.0f / s;
    }

    const int ar = t >> 2, ac = t & 3;
    const int asl = (ac ^ (ar & 3)) * 8;
    const _Float16* Ap = o_ws + (size_t)(mbase + ar) * DM + ac * 8;

    const int id0 = t, id1 = 256 + t;
    const int r0 = id0 >> 2, c0 = id0 & 3;
    const int r1 = id1 >> 2, c1 = id1 & 3;
    const int sl0 = (c0 ^ (r0 & 3)) * 8;
    const int sl1 = (c1 ^ (r1 & 3)) * 8;
    const float* Wp0 = Wo + (size_t)(nbase + r0) * DM + c0 * 8;
    const float* Wp1 = Wo + (size_t)(nbase + r1) * DM + c1 * 8;

    __syncthreads();  // Linv ready

    auto combine = [&](int kk) -> h8 {
        h8 x0 = *(const h8*)(Ap + kk);
        h8 x1 = *(const h8*)(Ap + kk + NSL * DM);
        const float li = Linv[ar][((kk + ac * 8) >> 6) & 7];
        union { h2 h[4]; h8 v; } u;
#pragma unroll
        for (int e = 0; e < 4; ++e) {
            float a0 = ((float)x0[2 * e]     + (float)x1[2 * e])     * li;
            float a1 = ((float)x0[2 * e + 1] + (float)x1[2 * e + 1]) * li;
            u.h[e] = pk2(a0, a1);
        }
        return u.v;
    };

    f16v acc[2] = {};

    {
        *(h8*)&As[0][ar * 32 + asl] = combine(0);
        float4 b00 = *(const float4*)(Wp0), b01 = *(const float4*)(Wp0 + 4);
        float4 b10 = *(const float4*)(Wp1), b11 = *(const float4*)(Wp1 + 4);
        *(h8*)&Bs[0][r0 * 32 + sl0] = cvt8(b00, b01);
        *(h8*)&Bs[0][r1 * 32 + sl1] = cvt8(b10, b11);
    }
    __syncthreads();

    int cur = 0;
    for (int step = 0; step < 16; ++step) {
        const int kn = (step + 1) * 32;
        const bool more = step + 1 < 16;
        h8 av;
        float4 b00, b01, b10, b11;
        if (more) {
            av  = combine(kn);
            b00 = *(const float4*)(Wp0 + kn); b01 = *(const float4*)(Wp0 + kn + 4);
            b10 = *(const float4*)(Wp1 + kn); b11 = *(const float4*)(Wp1 + kn + 4);
        }

        const _Float16* Ac = As[cur];
        const _Float16* Bc = Bs[cur];
        h8 af[2][2], bf[2];
#pragma unroll
        for (int ti = 0; ti < 2; ++ti)
#pragma unroll
            for (int s = 0; s < 2; ++s)
                af[ti][s] = *(const h8*)&Ac[(ti * 32 + l31) * 32 +
                                            (((2 * s + hi) ^ (l31 & 3)) << 3)];
#pragma unroll
        for (int s = 0; s < 2; ++s)
            bf[s] = *(const h8*)&Bc[(w * 32 + l31) * 32 +
                                    (((2 * s + hi) ^ (l31 & 3)) << 3)];
        __builtin_amdgcn_s_setprio(1);
#pragma unroll
        for (int ti = 0; ti < 2; ++ti)
#pragma unroll
            for (int s = 0; s < 2; ++s)
                acc[ti] = MFMA32(af[ti][s], bf[s], acc[ti]);
        __builtin_amdgcn_s_setprio(0);

        if (more) {
            const int nb2 = cur ^ 1;
            *(h8*)&As[nb2][ar * 32 + asl] = av;
            *(h8*)&Bs[nb2][r0 * 32 + sl0] = cvt8(b00, b01);
            *(h8*)&Bs[nb2][r1 * 32 + sl1] = cvt8(b10, b11);
        }
        __syncthreads();
        cur ^= 1;
    }

    const int n = nbase + w * 32 + l31;
    const float bb = bo[n];
#pragma unroll
    for (int ti = 0; ti < 2; ++ti) {
#pragma unroll
        for (int j = 0; j < 4; ++j) {
#pragma unroll
            for (int c = 0; c < 4; ++c) {
                const int m = mbase + ti * 32 + 8 * j + 4 * hi + c;
                out[(size_t)m * DM + n] = acc[ti][4 * j + c] + bb;
            }
        }
    }
}

// ---------------------------------------------------------------------------
extern "C" void kernel_launch(void* const* d_in, const int* in_sizes, int n_in,
                              void* d_out, int out_size, void* d_ws, size_t ws_size,
                              hipStream_t stream)
{
    const float* Q    = (const float*)d_in[0];
    const float* K    = (const float*)d_in[1];
    const float* V    = (const float*)d_in[2];
    const int*   mask = (const int*)d_in[3];
    const float* Wq   = (const float*)d_in[4];
    const float* bq   = (const float*)d_in[5];
    const float* Wk   = (const float*)d_in[6];
    const float* bk   = (const float*)d_in[7];
    const float* Wv   = (const float*)d_in[8];
    const float* bv   = (const float*)d_in[9];
    const float* Wo   = (const float*)d_in[10];
    const float* bo   = (const float*)d_in[11];
    float* out = (float*)d_out;

    _Float16* ws = (_Float16*)d_ws;
    const size_t per = (size_t)NB * NH * SL * DK;  // 4,194,304 halves
    _Float16* q_ws  = ws;
    _Float16* k_ws  = ws + per;
    _Float16* vT_ws = ws + 2 * per;
    _Float16* o_ws  = ws + 3 * per;                       // KSPL * per halves
    float*    l_ws  = (float*)(ws + 3 * per + KSPL * per);

    proj_qkv_kernel<<<dim3(768), 256, 0, stream>>>(
        Q, K, V, Wq, Wk, Wv, bq, bk, bv, q_ws, k_ws, vT_ws);

    attn_kernel<<<dim3(NB * NH, SL / QBLK, KSPL), 256, 0, stream>>>(
        q_ws, k_ws, vT_ws, mask, o_ws, l_ws);

    out_proj_kernel<<<dim3(512), 256, 0, stream>>>(o_ws, l_ws, Wo, bo, out);
}